// Round 13
// baseline (55.115 us; speedup 1.0000x reference)
//
#include <hip/hip_runtime.h>
#include <hip/hip_bf16.h>

namespace {
constexpr int kB = 2, kW = 5, kS = 5, kQ = 75, kC = 64, kHW = 441;
constexpr int kNP = 448;   // support positions padded (14 * 32)
constexpr int kMP = 448;   // query positions padded (14 col-tiles)
constexpr int kCHUNK = 112;
constexpr int kLDT = 65;   // odd stride -> conflict-free transpose scratch
constexpr int kSupUnits = kB * kW * 4;            // 40
constexpr int kUnits = kSupUnits + kB * kQ * 4;   // 640
constexpr int kTiles = kB * kQ * kW;              // 750
constexpr int kThreads = 448;                     // 7 waves: 2 col-tiles each
constexpr int kWaves = 7;
constexpr int kLdsRows = 416;                     // 13 nt-tiles in LDS (53248 B)
constexpr int kRep = 2;    // DIAGNOSTIC: surface main in rocprof top-5 (fills ~40us)

typedef short bf16x8 __attribute__((ext_vector_type(8)));
typedef float f32x16 __attribute__((ext_vector_type(16)));
typedef __attribute__((address_space(3))) unsigned int lds_u32;
typedef const __attribute__((address_space(1))) unsigned int gbl_u32;
}

// ---- prep (R2-validated, unchanged): shot-mean + L2-norm + transpose -> bf16 ----
__global__ __launch_bounds__(256) void prep_k(const float* __restrict__ sup,
                                              const float* __restrict__ qry,
                                              unsigned short* __restrict__ snT,
                                              unsigned short* __restrict__ qnT) {
  __shared__ float img_t[kCHUNK * kLDT];
  __shared__ float inv[kCHUNK];
  const int tid = threadIdx.x;
  const int blk = blockIdx.x;

  int m0, mcnt;
  unsigned short* dst;
  const bool is_sup = blk < kSupUnits;

  if (is_sup) {
    int bw = blk >> 2, chunk = blk & 3;
    m0 = chunk * kCHUNK;
    mcnt = min(kCHUNK, kHW - m0);
    const float* base = sup + (size_t)bw * kS * kC * kHW;
    for (int i = tid; i < kC * kCHUNK; i += 256) {
      int c = i / kCHUNK, mm = i % kCHUNK;
      float v = 0.f;
      if (mm < mcnt) {
        const float* p = base + (size_t)c * kHW + m0 + mm;
        float s = 0.f;
#pragma unroll
        for (int k = 0; k < kS; ++k) s += p[(size_t)k * kC * kHW];
        v = s * (1.f / kS);
      }
      img_t[mm * kLDT + c] = v;
    }
    dst = snT + (size_t)bw * kNP * kC;
  } else {
    int qb = blk - kSupUnits;
    int bq = qb >> 2, chunk = qb & 3;
    m0 = chunk * kCHUNK;
    mcnt = min(kCHUNK, kHW - m0);
    const float* base = qry + (size_t)bq * kC * kHW;
    for (int i = tid; i < kC * kCHUNK; i += 256) {
      int c = i / kCHUNK, mm = i % kCHUNK;
      img_t[mm * kLDT + c] = (mm < mcnt) ? base[(size_t)c * kHW + m0 + mm] : 0.f;
    }
    dst = qnT + (size_t)bq * kMP * kC;
  }
  __syncthreads();

  if (tid < kCHUNK) {
    float ss = 0.f;
#pragma unroll
    for (int c = 0; c < kC; ++c) { float v = img_t[tid * kLDT + c]; ss += v * v; }
    inv[tid] = 1.f / fmaxf(sqrtf(ss), 1e-12f);
  }
  __syncthreads();

  for (int i8 = tid; i8 < kCHUNK * 8; i8 += 256) {
    int m = i8 >> 3, c8 = (i8 & 7) * 8;
    float sc = inv[m];
    union { unsigned short u[8]; uint4 v; } pk;
#pragma unroll
    for (int j = 0; j < 8; ++j) {
      __hip_bfloat16 o = __float2bfloat16(img_t[m * kLDT + c8 + j] * sc);
      pk.u[j] = *reinterpret_cast<unsigned short*>(&o);
    }
    *reinterpret_cast<uint4*>(dst + ((size_t)(m0 + m) * kC + c8)) = pk.v;
  }
}

// ---- max helpers (R11-validated; backend auto-fuses fmaxf chains to v_max3.
//      R12 LESSON: inline-asm v_max3 reading MFMA-produced VGPRs corrupts —
//      hazard recognizer doesn't model asm operands. No asm here.) ----
__device__ __forceinline__ float max16_v(const f32x16& a) {
  float m0 = fmaxf(fmaxf(a[0], a[1]), a[2]);
  float m1 = fmaxf(fmaxf(a[3], a[4]), a[5]);
  float m2 = fmaxf(fmaxf(a[6], a[7]), a[8]);
  float m3 = fmaxf(fmaxf(a[9], a[10]), a[11]);
  float m4 = fmaxf(fmaxf(a[12], a[13]), a[14]);
  return fmaxf(fmaxf(fmaxf(m0, m1), m2), fmaxf(fmaxf(m3, m4), a[15]));
}
__device__ __forceinline__ float max12_v(const f32x16& a) {
  float m0 = fmaxf(fmaxf(a[0], a[1]), a[2]);
  float m1 = fmaxf(fmaxf(a[3], a[4]), a[5]);
  float m2 = fmaxf(fmaxf(a[6], a[7]), a[8]);
  float m3 = fmaxf(fmaxf(a[9], a[10]), a[11]);
  return fmaxf(fmaxf(m0, m1), fmaxf(m2, m3));
}

// ---- main (R11-validated structure, verbatim), kRep reps for rocprof visibility ----
__global__ __launch_bounds__(kThreads) void dn4_main_k(const unsigned short* __restrict__ qnT,
                                                       const unsigned short* __restrict__ snT,
                                                       float* __restrict__ out) {
  __shared__ __align__(16) unsigned short As[kLdsRows * kC];  // 53248 B
  __shared__ float part[kWaves];
  const int tid = threadIdx.x;

  // bijective XCD-chunked mapping (750 = 6*94 + 2*93)
  const int xcd = blockIdx.x & 7, jj = blockIdx.x >> 3;
  const int idx = (xcd < 6) ? xcd * 94 + jj : 564 + (xcd - 6) * 93 + jj;

  const int w = idx % kW;
  const int bq = idx / kW;
  const int b = bq / kQ;

  const int lane = tid & 63;
  const int lh = lane >> 5;
  const int lm = lane & 31;
  const int wid = tid >> 6;          // 0..6
  const int ct0 = wid * 2;           // 2 col-tiles per wave, 14 total

  const unsigned short* sb = snT + (size_t)(b * kW + w) * kNP * kC;
  const unsigned short* qb = qnT + (size_t)bq * kMP * kC;
  const char* sbase = (const char*)sb;

#pragma unroll 1
  for (int rep = 0; rep < kRep; ++rep) {  // DIAGNOSTIC repeat (idempotent, R8 pattern)
    // stage rows 0..415 (3328 chunks = 7*448 + 192): LDS linear dest,
    // pre-swizzled source (involution, validated R5..R11)
#pragma unroll
    for (int it = 0; it < 7; ++it) {
      int L = it * kThreads + tid;
      int srcj = (L & ~7) | ((L & 7) ^ ((L >> 3) & 7));
      __builtin_amdgcn_global_load_lds((gbl_u32*)(sbase + ((size_t)srcj << 4)),
                                       (lds_u32*)((char*)As + ((size_t)L << 4)), 16, 0, 0);
    }
    if (tid < 192) {   // waves 0..2 exactly (wave-uniform)
      int L = 7 * kThreads + tid;
      int srcj = (L & ~7) | ((L & 7) ^ ((L >> 3) & 7));
      __builtin_amdgcn_global_load_lds((gbl_u32*)(sbase + ((size_t)srcj << 4)),
                                       (lds_u32*)((char*)As + ((size_t)L << 4)), 16, 0, 0);
    }

    // query fragments in registers (independent of staging)
    bf16x8 bf[2][4];
#pragma unroll
    for (int ct = 0; ct < 2; ++ct) {
      int m = (ct0 + ct) * 32 + lm;
#pragma unroll
      for (int kk = 0; kk < 4; ++kk)
        bf[ct][kk] = *reinterpret_cast<const bf16x8*>(qb + (size_t)m * kC + kk * 16 + lh * 8);
    }

    // tail A-fragments (rows 416..447) from global into regs, pre-barrier
    bf16x8 aft[4];
    {
      const unsigned short* pt = sb + (size_t)(13 * 32 + lm) * kC + lh * 8;
#pragma unroll
      for (int kk = 0; kk < 4; ++kk)
        aft[kk] = *reinterpret_cast<const bf16x8*>(pt + kk * 16);
    }

    f32x16 z;
#pragma unroll
    for (int r = 0; r < 16; ++r) z[r] = 0.f;
    float rm[2] = {-INFINITY, -INFINITY};

    __syncthreads();   // the ONE staging barrier (drains gload_lds)

    // 13 nt-tiles from LDS (runtime loop: full unroll spills — R6 lesson)
#pragma unroll 1
    for (int nt = 0; nt < 13; ++nt) {
      bf16x8 af[4];
      int n = nt * 32 + lm;
#pragma unroll
      for (int kk = 0; kk < 4; ++kk) {
        int k16 = kk * 2 + lh;
        af[kk] = *reinterpret_cast<const bf16x8*>(As + ((size_t)(n * 8 + (k16 ^ (n & 7))) << 3));
      }
#pragma unroll
      for (int ct = 0; ct < 2; ++ct) {
        f32x16 acc = z;
#pragma unroll
        for (int kk = 0; kk < 4; ++kk)
          acc = __builtin_amdgcn_mfma_f32_32x32x16_bf16(af[kk], bf[ct][kk], acc, 0, 0, 0);
        rm[ct] = fmaxf(rm[ct], max16_v(acc));
      }
    }

    // tail tile nt=13 from registers: rows 416..447; valid < 441 -> tile row <= 24.
    // row = (r&3)+8*(r>>2)+4*lh: lh0 invalid regs {13,14,15}, lh1 invalid {12..15}
#pragma unroll
    for (int ct = 0; ct < 2; ++ct) {
      f32x16 acc = z;
#pragma unroll
      for (int kk = 0; kk < 4; ++kk)
        acc = __builtin_amdgcn_mfma_f32_32x32x16_bf16(aft[kk], bf[ct][kk], acc, 0, 0, 0);
      float t = max12_v(acc);
      if (lh == 0) t = fmaxf(t, acc[12]);  // row 24 still valid
      rm[ct] = fmaxf(rm[ct], t);
    }

    // combine complementary row-halves, then sum this wave's 64 columns
    float s = fmaxf(rm[0], __shfl_xor(rm[0], 32, 64)) +
              fmaxf(rm[1], __shfl_xor(rm[1], 32, 64));
#pragma unroll
    for (int off = 1; off < 32; off <<= 1) s += __shfl_xor(s, off, 64);

    if (lane == 0) part[wid] = s;
    __syncthreads();
    if (tid == 0) {
      float t = 0.f;
#pragma unroll
      for (int v = 0; v < kWaves; ++v) t += part[v];
      out[idx] = t;
    }
    __syncthreads();   // all reads of As/part done before next rep restages
  }
}

extern "C" void kernel_launch(void* const* d_in, const int* in_sizes, int n_in,
                              void* d_out, int out_size, void* d_ws, size_t ws_size,
                              hipStream_t stream) {
  const float* sup = (const float*)d_in[0];
  const float* qry = (const float*)d_in[2];
  float* out = (float*)d_out;

  unsigned short* snT = (unsigned short*)d_ws;                 // 573,440 B
  unsigned short* qnT = snT + (size_t)kB * kW * kNP * kC;      // 8,601,600 B

  prep_k<<<kUnits, 256, 0, stream>>>(sup, qry, snT, qnT);
  dn4_main_k<<<kTiles, kThreads, 0, stream>>>(qnT, snT, out);
}

// Round 14
// 38.907 us; speedup vs baseline: 1.4166x; 1.4166x over previous
//
#include <hip/hip_runtime.h>
#include <hip/hip_bf16.h>

namespace {
constexpr int kB = 2, kW = 5, kS = 5, kQ = 75, kC = 64, kHW = 441;
constexpr int kNP = 448;   // support positions padded (14 * 32)
constexpr int kMP = 448;   // query positions padded (14 col-tiles)
constexpr int kCHUNK = 112;
constexpr int kLDT = 65;   // odd stride -> conflict-free transpose scratch
constexpr int kSupUnits = kB * kW * 4;            // 40
constexpr int kUnits = kSupUnits + kB * kQ * 4;   // 640
constexpr int kTiles = kB * kQ * kW;              // 750
constexpr int kThreads = 448;                     // 7 waves: 2 col-tiles each
constexpr int kWaves = 7;

typedef short bf16x8 __attribute__((ext_vector_type(8)));
typedef float f32x16 __attribute__((ext_vector_type(16)));
typedef __attribute__((address_space(3))) unsigned int lds_u32;
typedef const __attribute__((address_space(1))) unsigned int gbl_u32;
}

// ---- prep (R2-validated, unchanged): shot-mean + L2-norm + transpose -> bf16 ----
__global__ __launch_bounds__(256) void prep_k(const float* __restrict__ sup,
                                              const float* __restrict__ qry,
                                              unsigned short* __restrict__ snT,
                                              unsigned short* __restrict__ qnT) {
  __shared__ float img_t[kCHUNK * kLDT];
  __shared__ float inv[kCHUNK];
  const int tid = threadIdx.x;
  const int blk = blockIdx.x;

  int m0, mcnt;
  unsigned short* dst;
  const bool is_sup = blk < kSupUnits;

  if (is_sup) {
    int bw = blk >> 2, chunk = blk & 3;
    m0 = chunk * kCHUNK;
    mcnt = min(kCHUNK, kHW - m0);
    const float* base = sup + (size_t)bw * kS * kC * kHW;
    for (int i = tid; i < kC * kCHUNK; i += 256) {
      int c = i / kCHUNK, mm = i % kCHUNK;
      float v = 0.f;
      if (mm < mcnt) {
        const float* p = base + (size_t)c * kHW + m0 + mm;
        float s = 0.f;
#pragma unroll
        for (int k = 0; k < kS; ++k) s += p[(size_t)k * kC * kHW];
        v = s * (1.f / kS);
      }
      img_t[mm * kLDT + c] = v;
    }
    dst = snT + (size_t)bw * kNP * kC;
  } else {
    int qb = blk - kSupUnits;
    int bq = qb >> 2, chunk = qb & 3;
    m0 = chunk * kCHUNK;
    mcnt = min(kCHUNK, kHW - m0);
    const float* base = qry + (size_t)bq * kC * kHW;
    for (int i = tid; i < kC * kCHUNK; i += 256) {
      int c = i / kCHUNK, mm = i % kCHUNK;
      img_t[mm * kLDT + c] = (mm < mcnt) ? base[(size_t)c * kHW + m0 + mm] : 0.f;
    }
    dst = qnT + (size_t)bq * kMP * kC;
  }
  __syncthreads();

  if (tid < kCHUNK) {
    float ss = 0.f;
#pragma unroll
    for (int c = 0; c < kC; ++c) { float v = img_t[tid * kLDT + c]; ss += v * v; }
    inv[tid] = 1.f / fmaxf(sqrtf(ss), 1e-12f);
  }
  __syncthreads();

  for (int i8 = tid; i8 < kCHUNK * 8; i8 += 256) {
    int m = i8 >> 3, c8 = (i8 & 7) * 8;
    float sc = inv[m];
    union { unsigned short u[8]; uint4 v; } pk;
#pragma unroll
    for (int j = 0; j < 8; ++j) {
      __hip_bfloat16 o = __float2bfloat16(img_t[m * kLDT + c8 + j] * sc);
      pk.u[j] = *reinterpret_cast<unsigned short*>(&o);
    }
    *reinterpret_cast<uint4*>(dst + ((size_t)(m0 + m) * kC + c8)) = pk.v;
  }
}

// ---- max helpers (validated; NO inline asm — R12 lesson) ----
__device__ __forceinline__ float max16_v(const f32x16& a) {
  float m0 = fmaxf(fmaxf(a[0], a[1]), a[2]);
  float m1 = fmaxf(fmaxf(a[3], a[4]), a[5]);
  float m2 = fmaxf(fmaxf(a[6], a[7]), a[8]);
  float m3 = fmaxf(fmaxf(a[9], a[10]), a[11]);
  float m4 = fmaxf(fmaxf(a[12], a[13]), a[14]);
  return fmaxf(fmaxf(fmaxf(m0, m1), m2), fmaxf(fmaxf(m3, m4), a[15]));
}
__device__ __forceinline__ float max12_v(const f32x16& a) {
  float m0 = fmaxf(fmaxf(a[0], a[1]), a[2]);
  float m1 = fmaxf(fmaxf(a[3], a[4]), a[5]);
  float m2 = fmaxf(fmaxf(a[6], a[7]), a[8]);
  float m3 = fmaxf(fmaxf(a[9], a[10]), a[11]);
  return fmaxf(fmaxf(m0, m1), fmaxf(m2, m3));
}

// ---- main: full 448-row LDS staging, counted-vmcnt SPLIT barrier (T3/T4):
//      vmcnt(4)+s_barrier -> compute tiles 0..6 while rounds 4..7 land;
//      vmcnt(0)+s_barrier -> tiles 7..13. Hides ~half the cold staging
//      latency under compute (R13: cold rep 30us vs warm 15.7us). ----
__global__ __launch_bounds__(kThreads) void dn4_main_k(const unsigned short* __restrict__ qnT,
                                                       const unsigned short* __restrict__ snT,
                                                       float* __restrict__ out) {
  __shared__ __align__(16) unsigned short As[kNP * kC];  // 57344 B (2 blocks/CU)
  __shared__ float part[kWaves];
  const int tid = threadIdx.x;

  // bijective XCD-chunked mapping (750 = 6*94 + 2*93)
  const int xcd = blockIdx.x & 7, jj = blockIdx.x >> 3;
  const int idx = (xcd < 6) ? xcd * 94 + jj : 564 + (xcd - 6) * 93 + jj;

  const int w = idx % kW;
  const int bq = idx / kW;
  const int b = bq / kQ;

  const int lane = tid & 63;
  const int lh = lane >> 5;
  const int lm = lane & 31;
  const int wid = tid >> 6;          // 0..6
  const int ct0 = wid * 2;           // 2 col-tiles per wave, 14 total

  const unsigned short* sb = snT + (size_t)(b * kW + w) * kNP * kC;
  const unsigned short* qb = qnT + (size_t)bq * kMP * kC;
  const char* sbase = (const char*)sb;

  // query fragments issued first (plain vmem; compiler tracks their deps)
  bf16x8 bf[2][4];
#pragma unroll
  for (int ct = 0; ct < 2; ++ct) {
    int m = (ct0 + ct) * 32 + lm;
#pragma unroll
    for (int kk = 0; kk < 4; ++kk)
      bf[ct][kk] = *reinterpret_cast<const bf16x8*>(qb + (size_t)m * kC + kk * 16 + lh * 8);
  }

  // stage ALL 448 rows: 3584 chunks = 8 uniform rounds x 448 threads.
  // LDS linear dest, pre-swizzled source (involution, validated R5..R13).
  // Round it covers rows it*56..it*56+55 -> rounds 0..3 = rows 0..223 (tiles 0..6).
#pragma unroll
  for (int it = 0; it < 8; ++it) {
    int L = it * kThreads + tid;
    int srcj = (L & ~7) | ((L & 7) ^ ((L >> 3) & 7));
    __builtin_amdgcn_global_load_lds((gbl_u32*)(sbase + ((size_t)srcj << 4)),
                                     (lds_u32*)((char*)As + ((size_t)L << 4)), 16, 0, 0);
  }

  f32x16 z;
#pragma unroll
  for (int r = 0; r < 16; ++r) z[r] = 0.f;
  float rm[2] = {-INFINITY, -INFINITY};

  // wait: everything except the last 4 staging rounds (conservative under any
  // load sinking — staging ops hold program order above this asm). Rule #18:
  // sched_barrier(0) after the waitcnt.
  asm volatile("s_waitcnt vmcnt(4)" ::: "memory");
  __builtin_amdgcn_sched_barrier(0);
  __builtin_amdgcn_s_barrier();

  // tiles 0..6 from LDS rows 0..223 (runtime loop: full unroll spills — R6)
#pragma unroll 1
  for (int nt = 0; nt < 7; ++nt) {
    bf16x8 af[4];
    int n = nt * 32 + lm;
#pragma unroll
    for (int kk = 0; kk < 4; ++kk) {
      int k16 = kk * 2 + lh;
      af[kk] = *reinterpret_cast<const bf16x8*>(As + ((size_t)(n * 8 + (k16 ^ (n & 7))) << 3));
    }
#pragma unroll
    for (int ct = 0; ct < 2; ++ct) {
      f32x16 acc = z;
#pragma unroll
      for (int kk = 0; kk < 4; ++kk)
        acc = __builtin_amdgcn_mfma_f32_32x32x16_bf16(af[kk], bf[ct][kk], acc, 0, 0, 0);
      rm[ct] = fmaxf(rm[ct], max16_v(acc));
    }
  }

  // all staging complete, then second barrier
  asm volatile("s_waitcnt vmcnt(0)" ::: "memory");
  __builtin_amdgcn_sched_barrier(0);
  __builtin_amdgcn_s_barrier();

  // tiles 7..12
#pragma unroll 1
  for (int nt = 7; nt < 13; ++nt) {
    bf16x8 af[4];
    int n = nt * 32 + lm;
#pragma unroll
    for (int kk = 0; kk < 4; ++kk) {
      int k16 = kk * 2 + lh;
      af[kk] = *reinterpret_cast<const bf16x8*>(As + ((size_t)(n * 8 + (k16 ^ (n & 7))) << 3));
    }
#pragma unroll
    for (int ct = 0; ct < 2; ++ct) {
      f32x16 acc = z;
#pragma unroll
      for (int kk = 0; kk < 4; ++kk)
        acc = __builtin_amdgcn_mfma_f32_32x32x16_bf16(af[kk], bf[ct][kk], acc, 0, 0, 0);
      rm[ct] = fmaxf(rm[ct], max16_v(acc));
    }
  }

  // tail tile nt=13 from LDS (rows 416..447; prep zero-pads 441..447 but mask
  // anyway — zeros could beat all-negative sims). Valid tile row <= 24:
  // row = (r&3)+8*(r>>2)+4*lh: lh0 invalid regs {13,14,15}, lh1 invalid {12..15}
  {
    bf16x8 af[4];
    int n = 13 * 32 + lm;
#pragma unroll
    for (int kk = 0; kk < 4; ++kk) {
      int k16 = kk * 2 + lh;
      af[kk] = *reinterpret_cast<const bf16x8*>(As + ((size_t)(n * 8 + (k16 ^ (n & 7))) << 3));
    }
#pragma unroll
    for (int ct = 0; ct < 2; ++ct) {
      f32x16 acc = z;
#pragma unroll
      for (int kk = 0; kk < 4; ++kk)
        acc = __builtin_amdgcn_mfma_f32_32x32x16_bf16(af[kk], bf[ct][kk], acc, 0, 0, 0);
      float t = max12_v(acc);
      if (lh == 0) t = fmaxf(t, acc[12]);  // row 24 still valid
      rm[ct] = fmaxf(rm[ct], t);
    }
  }

  // combine complementary row-halves, then sum this wave's 64 columns
  float s = fmaxf(rm[0], __shfl_xor(rm[0], 32, 64)) +
            fmaxf(rm[1], __shfl_xor(rm[1], 32, 64));
#pragma unroll
  for (int off = 1; off < 32; off <<= 1) s += __shfl_xor(s, off, 64);

  if (lane == 0) part[wid] = s;
  __syncthreads();
  if (tid == 0) {
    float t = 0.f;
#pragma unroll
    for (int v = 0; v < kWaves; ++v) t += part[v];
    out[idx] = t;
  }
}

extern "C" void kernel_launch(void* const* d_in, const int* in_sizes, int n_in,
                              void* d_out, int out_size, void* d_ws, size_t ws_size,
                              hipStream_t stream) {
  const float* sup = (const float*)d_in[0];
  const float* qry = (const float*)d_in[2];
  float* out = (float*)d_out;

  unsigned short* snT = (unsigned short*)d_ws;                 // 573,440 B
  unsigned short* qnT = snT + (size_t)kB * kW * kNP * kC;      // 8,601,600 B

  prep_k<<<kUnits, 256, 0, stream>>>(sup, qry, snT, qnT);
  dn4_main_k<<<kTiles, kThreads, 0, stream>>>(qnT, snT, out);
}

// Round 15
// 38.630 us; speedup vs baseline: 1.4267x; 1.0072x over previous
//
#include <hip/hip_runtime.h>
#include <hip/hip_bf16.h>

namespace {
constexpr int kB = 2, kW = 5, kS = 5, kQ = 75, kC = 64, kHW = 441;
constexpr int kNP = 448;   // support positions padded (14 * 32)
constexpr int kMP = 448;   // query positions padded (14 col-tiles)
constexpr int kCHUNK = 112;
constexpr int kLDT = 65;   // odd stride -> conflict-free transpose scratch
constexpr int kTiles = kB * kQ * kW;              // 750
constexpr int kThreads = 448;                     // 7 waves: 2 col-tiles each
constexpr int kWaves = 7;
constexpr int kPrepGrid = 8 * 81;                 // xcd-targeted prep blocks

typedef short bf16x8 __attribute__((ext_vector_type(8)));
typedef float f32x16 __attribute__((ext_vector_type(16)));
typedef __attribute__((address_space(3))) unsigned int lds_u32;
typedef const __attribute__((address_space(1))) unsigned int gbl_u32;
}

// ---- prep: shot-mean + L2-norm + transpose -> bf16 (R2-validated body).
//      NEW (R15): block->XCD co-location. Main maps tile idx to xcd via
//      contiguous chunks (94/94/94/94/94/94/93/93); query image bq is consumed
//      by main blocks on xcd X(bq). Prep block bid runs on xcd bid%8 (HW
//      round-robin, m09/m157), so we assign each xcd's prep slots exactly the
//      images its main blocks will read -> qnT is already in the right L2. ----
__global__ __launch_bounds__(256) void prep_k(const float* __restrict__ sup,
                                              const float* __restrict__ qry,
                                              unsigned short* __restrict__ snT,
                                              unsigned short* __restrict__ qnT) {
  __shared__ float img_t[kCHUNK * kLDT];
  __shared__ float inv[kCHUNK];
  const int tid = threadIdx.x;
  const int x = blockIdx.x & 7;    // target xcd
  const int j = blockIdx.x >> 3;   // slot within xcd: 0..80

  // query-image range for main-xcd x (monotone tile->xcd map, ceil(start/5))
  const int start0 = (x < 6) ? 94 * x : 564 + 93 * (x - 6);
  const int start1 = (x + 1 < 6) ? 94 * (x + 1) : 564 + 93 * (x + 1 - 6);
  const int lo = (start0 + 4) / 5, hi = (start1 + 4) / 5;
  const int cnt = hi - lo;                  // 18 or 19 images
  const int nq = 4 * cnt;                   // query slots on this xcd

  bool is_sup;
  int bw = 0, bq = 0, chunk;
  if (j < nq) {
    is_sup = false;
    bq = lo + (j >> 2);
    chunk = j & 3;
  } else {
    int js = j - nq;
    if (js >= 5) return;                    // idle slot
    is_sup = true;
    int u = x + 8 * js;                     // support units 0..39, each once
    bw = u >> 2;
    chunk = u & 3;
  }

  const int m0 = chunk * kCHUNK;
  const int mcnt = min(kCHUNK, kHW - m0);
  unsigned short* dst;

  if (is_sup) {
    const float* base = sup + (size_t)bw * kS * kC * kHW;
    for (int i = tid; i < kC * kCHUNK; i += 256) {
      int c = i / kCHUNK, mm = i % kCHUNK;
      float v = 0.f;
      if (mm < mcnt) {
        const float* p = base + (size_t)c * kHW + m0 + mm;
        float s = 0.f;
#pragma unroll
        for (int k = 0; k < kS; ++k) s += p[(size_t)k * kC * kHW];
        v = s * (1.f / kS);
      }
      img_t[mm * kLDT + c] = v;
    }
    dst = snT + (size_t)bw * kNP * kC;
  } else {
    const float* base = qry + (size_t)bq * kC * kHW;
    for (int i = tid; i < kC * kCHUNK; i += 256) {
      int c = i / kCHUNK, mm = i % kCHUNK;
      img_t[mm * kLDT + c] = (mm < mcnt) ? base[(size_t)c * kHW + m0 + mm] : 0.f;
    }
    dst = qnT + (size_t)bq * kMP * kC;
  }
  __syncthreads();

  if (tid < kCHUNK) {
    float ss = 0.f;
#pragma unroll
    for (int c = 0; c < kC; ++c) { float v = img_t[tid * kLDT + c]; ss += v * v; }
    inv[tid] = 1.f / fmaxf(sqrtf(ss), 1e-12f);
  }
  __syncthreads();

  for (int i8 = tid; i8 < kCHUNK * 8; i8 += 256) {
    int m = i8 >> 3, c8 = (i8 & 7) * 8;
    float sc = inv[m];
    union { unsigned short u[8]; uint4 v; } pk;
#pragma unroll
    for (int jj = 0; jj < 8; ++jj) {
      __hip_bfloat16 o = __float2bfloat16(img_t[m * kLDT + c8 + jj] * sc);
      pk.u[jj] = *reinterpret_cast<unsigned short*>(&o);
    }
    *reinterpret_cast<uint4*>(dst + ((size_t)(m0 + m) * kC + c8)) = pk.v;
  }
}

// ---- max helpers (validated; NO inline asm — R12 lesson) ----
__device__ __forceinline__ float max16_v(const f32x16& a) {
  float m0 = fmaxf(fmaxf(a[0], a[1]), a[2]);
  float m1 = fmaxf(fmaxf(a[3], a[4]), a[5]);
  float m2 = fmaxf(fmaxf(a[6], a[7]), a[8]);
  float m3 = fmaxf(fmaxf(a[9], a[10]), a[11]);
  float m4 = fmaxf(fmaxf(a[12], a[13]), a[14]);
  return fmaxf(fmaxf(fmaxf(m0, m1), m2), fmaxf(fmaxf(m3, m4), a[15]));
}
__device__ __forceinline__ float max12_v(const f32x16& a) {
  float m0 = fmaxf(fmaxf(a[0], a[1]), a[2]);
  float m1 = fmaxf(fmaxf(a[3], a[4]), a[5]);
  float m2 = fmaxf(fmaxf(a[6], a[7]), a[8]);
  float m3 = fmaxf(fmaxf(a[9], a[10]), a[11]);
  return fmaxf(fmaxf(m0, m1), fmaxf(m2, m3));
}

// ---- main (R14-validated, unchanged): full staging, counted-vmcnt split ----
__global__ __launch_bounds__(kThreads) void dn4_main_k(const unsigned short* __restrict__ qnT,
                                                       const unsigned short* __restrict__ snT,
                                                       float* __restrict__ out) {
  __shared__ __align__(16) unsigned short As[kNP * kC];  // 57344 B (2 blocks/CU)
  __shared__ float part[kWaves];
  const int tid = threadIdx.x;

  // bijective XCD-chunked mapping (750 = 6*94 + 2*93)
  const int xcd = blockIdx.x & 7, jj = blockIdx.x >> 3;
  const int idx = (xcd < 6) ? xcd * 94 + jj : 564 + (xcd - 6) * 93 + jj;

  const int w = idx % kW;
  const int bq = idx / kW;
  const int b = bq / kQ;

  const int lane = tid & 63;
  const int lh = lane >> 5;
  const int lm = lane & 31;
  const int wid = tid >> 6;          // 0..6
  const int ct0 = wid * 2;           // 2 col-tiles per wave, 14 total

  const unsigned short* sb = snT + (size_t)(b * kW + w) * kNP * kC;
  const unsigned short* qb = qnT + (size_t)bq * kMP * kC;
  const char* sbase = (const char*)sb;

  // query fragments issued first
  bf16x8 bf[2][4];
#pragma unroll
  for (int ct = 0; ct < 2; ++ct) {
    int m = (ct0 + ct) * 32 + lm;
#pragma unroll
    for (int kk = 0; kk < 4; ++kk)
      bf[ct][kk] = *reinterpret_cast<const bf16x8*>(qb + (size_t)m * kC + kk * 16 + lh * 8);
  }

  // stage all 448 rows: 3584 chunks = 8 rounds x 448. LDS linear dest,
  // pre-swizzled source (involution, validated R5..R14).
#pragma unroll
  for (int it = 0; it < 8; ++it) {
    int L = it * kThreads + tid;
    int srcj = (L & ~7) | ((L & 7) ^ ((L >> 3) & 7));
    __builtin_amdgcn_global_load_lds((gbl_u32*)(sbase + ((size_t)srcj << 4)),
                                     (lds_u32*)((char*)As + ((size_t)L << 4)), 16, 0, 0);
  }

  f32x16 z;
#pragma unroll
  for (int r = 0; r < 16; ++r) z[r] = 0.f;
  float rm[2] = {-INFINITY, -INFINITY};

  asm volatile("s_waitcnt vmcnt(4)" ::: "memory");   // bf + rounds 0..3 landed
  __builtin_amdgcn_sched_barrier(0);
  __builtin_amdgcn_s_barrier();

  // tiles 0..6 from LDS rows 0..223 (runtime loop: full unroll spills — R6)
#pragma unroll 1
  for (int nt = 0; nt < 7; ++nt) {
    bf16x8 af[4];
    int n = nt * 32 + lm;
#pragma unroll
    for (int kk = 0; kk < 4; ++kk) {
      int k16 = kk * 2 + lh;
      af[kk] = *reinterpret_cast<const bf16x8*>(As + ((size_t)(n * 8 + (k16 ^ (n & 7))) << 3));
    }
#pragma unroll
    for (int ct = 0; ct < 2; ++ct) {
      f32x16 acc = z;
#pragma unroll
      for (int kk = 0; kk < 4; ++kk)
        acc = __builtin_amdgcn_mfma_f32_32x32x16_bf16(af[kk], bf[ct][kk], acc, 0, 0, 0);
      rm[ct] = fmaxf(rm[ct], max16_v(acc));
    }
  }

  asm volatile("s_waitcnt vmcnt(0)" ::: "memory");   // all staging complete
  __builtin_amdgcn_sched_barrier(0);
  __builtin_amdgcn_s_barrier();

  // tiles 7..12
#pragma unroll 1
  for (int nt = 7; nt < 13; ++nt) {
    bf16x8 af[4];
    int n = nt * 32 + lm;
#pragma unroll
    for (int kk = 0; kk < 4; ++kk) {
      int k16 = kk * 2 + lh;
      af[kk] = *reinterpret_cast<const bf16x8*>(As + ((size_t)(n * 8 + (k16 ^ (n & 7))) << 3));
    }
#pragma unroll
    for (int ct = 0; ct < 2; ++ct) {
      f32x16 acc = z;
#pragma unroll
      for (int kk = 0; kk < 4; ++kk)
        acc = __builtin_amdgcn_mfma_f32_32x32x16_bf16(af[kk], bf[ct][kk], acc, 0, 0, 0);
      rm[ct] = fmaxf(rm[ct], max16_v(acc));
    }
  }

  // tail tile nt=13 (rows 416..447; valid tile row <= 24; prep zero-pads but
  // mask anyway — zeros could beat all-negative sims).
  // row = (r&3)+8*(r>>2)+4*lh: lh0 invalid regs {13,14,15}, lh1 invalid {12..15}
  {
    bf16x8 af[4];
    int n = 13 * 32 + lm;
#pragma unroll
    for (int kk = 0; kk < 4; ++kk) {
      int k16 = kk * 2 + lh;
      af[kk] = *reinterpret_cast<const bf16x8*>(As + ((size_t)(n * 8 + (k16 ^ (n & 7))) << 3));
    }
#pragma unroll
    for (int ct = 0; ct < 2; ++ct) {
      f32x16 acc = z;
#pragma unroll
      for (int kk = 0; kk < 4; ++kk)
        acc = __builtin_amdgcn_mfma_f32_32x32x16_bf16(af[kk], bf[ct][kk], acc, 0, 0, 0);
      float t = max12_v(acc);
      if (lh == 0) t = fmaxf(t, acc[12]);  // row 24 still valid
      rm[ct] = fmaxf(rm[ct], t);
    }
  }

  // combine complementary row-halves, then sum this wave's 64 columns
  float s = fmaxf(rm[0], __shfl_xor(rm[0], 32, 64)) +
            fmaxf(rm[1], __shfl_xor(rm[1], 32, 64));
#pragma unroll
  for (int off = 1; off < 32; off <<= 1) s += __shfl_xor(s, off, 64);

  if (lane == 0) part[wid] = s;
  __syncthreads();
  if (tid == 0) {
    float t = 0.f;
#pragma unroll
    for (int v = 0; v < kWaves; ++v) t += part[v];
    out[idx] = t;
  }
}

extern "C" void kernel_launch(void* const* d_in, const int* in_sizes, int n_in,
                              void* d_out, int out_size, void* d_ws, size_t ws_size,
                              hipStream_t stream) {
  const float* sup = (const float*)d_in[0];
  const float* qry = (const float*)d_in[2];
  float* out = (float*)d_out;

  unsigned short* snT = (unsigned short*)d_ws;                 // 573,440 B
  unsigned short* qnT = snT + (size_t)kB * kW * kNP * kC;      // 8,601,600 B

  prep_k<<<kPrepGrid, 256, 0, stream>>>(sup, qry, snT, qnT);
  dn4_main_k<<<kTiles, kThreads, 0, stream>>>(qnT, snT, out);
}